// Round 2
// baseline (364.924 us; speedup 1.0000x reference)
//
#include <hip/hip_runtime.h>
#include <hip/hip_bf16.h>
#include <math.h>

#define J 75
#define EDGES 300
#define MAXE (EDGES + J)   // 375 with self loops
#define HID 64
#define OUTF 256
#define BT 2048

// ---------------- Kernel 0: build CSR (dst -> [src, norm]) ----------------
__global__ void build_csr_kernel(const int* __restrict__ ei,
                                 int* __restrict__ csr_off,
                                 int* __restrict__ csr_src,
                                 float* __restrict__ csr_norm) {
    __shared__ int   deg[J];
    __shared__ int   off[J + 1];
    __shared__ int   cur[J];
    __shared__ float dis[J];
    const int tid = threadIdx.x;

    if (tid < J) { deg[tid] = 1; cur[tid] = 0; }   // self-loop contributes 1
    __syncthreads();
    for (int e = tid; e < EDGES; e += blockDim.x)
        atomicAdd(&deg[ei[EDGES + e]], 1);         // dst row = ei[1][e]
    __syncthreads();
    if (tid == 0) {
        int s = 0;
        for (int j = 0; j < J; ++j) { off[j] = s; s += deg[j]; }
        off[J] = s;                                // == MAXE
    }
    if (tid < J) dis[tid] = rsqrtf((float)deg[tid]);
    __syncthreads();
    for (int e = tid; e < EDGES; e += blockDim.x) {
        int s = ei[e], d = ei[EDGES + e];
        int p = off[d] + atomicAdd(&cur[d], 1);
        csr_src[p]  = s;
        csr_norm[p] = dis[s] * dis[d];
    }
    for (int j = tid; j < J; j += blockDim.x) {    // self loops
        int p = off[j] + atomicAdd(&cur[j], 1);
        csr_src[p]  = j;
        csr_norm[p] = dis[j] * dis[j];
    }
    __syncthreads();
    for (int j = tid; j <= J; j += blockDim.x) csr_off[j] = off[j];
}

__device__ __forceinline__ float gelu_exact(float v) {
    return 0.5f * v * (1.0f + erff(v * 0.70710678118654752f));
}

// ---------------- Kernel 1: fully fused 2-layer GCN, one block per (b,t) ----------------
__global__ void __launch_bounds__(256, 2) gcn_fused_kernel(
        const float* __restrict__ xg,
        const float* __restrict__ W1,
        const float* __restrict__ b1,
        const float* __restrict__ W2,
        const float* __restrict__ b2,
        const int*   __restrict__ csr_off,
        const int*   __restrict__ csr_src,
        const float* __restrict__ csr_norm,
        float* __restrict__ outg) {
    __shared__ float xs[J * 3];
    __shared__ float ax[J * 3];
    __shared__ float Bs[J * HID];
    __shared__ __align__(16) float Cs[J * HID];
    __shared__ float W1s[3 * HID];
    __shared__ float b1s[HID];
    __shared__ int   offs[J + 1];
    __shared__ int   srcs[MAXE];
    __shared__ float nrms[MAXE];

    const int tid = threadIdx.x;
    const int bt  = blockIdx.x;

    // ---- stage graph + small weights + x tile ----
    if (tid < J + 1) offs[tid] = csr_off[tid];
    for (int i = tid; i < MAXE; i += 256) { srcs[i] = csr_src[i]; nrms[i] = csr_norm[i]; }
    if (tid < 3 * HID) W1s[tid] = W1[tid];
    if (tid < HID)     b1s[tid] = b1[tid];
    for (int i = tid; i < J * 3; i += 256)
        xs[i] = xg[bt * (J * 3) + i];
    __syncthreads();

    // ---- aggregate x over graph (75 x 3) ----
    for (int idx = tid; idx < J * 3; idx += 256) {
        int j = idx / 3, d = idx - j * 3;
        float s = 0.f;
        int p0 = offs[j], p1 = offs[j + 1];
        for (int p = p0; p < p1; ++p) s += nrms[p] * xs[srcs[p] * 3 + d];
        ax[idx] = s;
    }
    __syncthreads();

    // ---- layer 1: matmul (3->64) + bias + gelu ----
    for (int idx = tid; idx < J * HID; idx += 256) {
        int j = idx >> 6, f = idx & 63;
        float v = ax[j * 3 + 0] * W1s[0 * HID + f]
                + ax[j * 3 + 1] * W1s[1 * HID + f]
                + ax[j * 3 + 2] * W1s[2 * HID + f]
                + b1s[f];
        Bs[idx] = gelu_exact(v);
    }
    __syncthreads();

    // ---- aggregate layer-1 activations (75 x 64) ----
    for (int idx = tid; idx < J * HID; idx += 256) {
        int j = idx >> 6, f = idx & 63;
        float s = 0.f;
        int p0 = offs[j], p1 = offs[j + 1];
        for (int p = p0; p < p1; ++p) s += nrms[p] * Bs[srcs[p] * HID + f];
        Cs[idx] = s;
    }
    __syncthreads();

    // ---- layer 2: out[j][o] = gelu(sum_f Cs[j][f] * W2[f][o] + b2[o]); o = tid ----
    const int o = tid;
    float w2c[HID];
#pragma unroll
    for (int f = 0; f < HID; ++f)
        w2c[f] = W2[f * OUTF + o];                 // coalesced, L2-resident
    const float bias = b2[o];

    const float4* Cs4 = (const float4*)Cs;
    float* op = outg + (size_t)bt * (J * OUTF) + o;
    for (int j = 0; j < J; ++j) {
        float acc = bias;
#pragma unroll
        for (int q = 0; q < HID / 4; ++q) {
            float4 c = Cs4[j * (HID / 4) + q];     // wave-uniform broadcast read
            acc += c.x * w2c[4 * q + 0] + c.y * w2c[4 * q + 1]
                 + c.z * w2c[4 * q + 2] + c.w * w2c[4 * q + 3];
        }
        op[j * OUTF] = gelu_exact(acc);
    }
}

extern "C" void kernel_launch(void* const* d_in, const int* in_sizes, int n_in,
                              void* d_out, int out_size, void* d_ws, size_t ws_size,
                              hipStream_t stream) {
    const float* x  = (const float*)d_in[0];
    const int*   ei = (const int*)d_in[1];
    const float* W1 = (const float*)d_in[2];
    const float* b1 = (const float*)d_in[3];
    const float* W2 = (const float*)d_in[4];
    const float* b2 = (const float*)d_in[5];
    float* out = (float*)d_out;

    char* ws = (char*)d_ws;
    int*   csr_off  = (int*)ws;                       // 76 ints
    int*   csr_src  = (int*)(ws + 512);               // 375 ints
    float* csr_norm = (float*)(ws + 512 + 2048);      // 375 floats

    build_csr_kernel<<<1, 256, 0, stream>>>(ei, csr_off, csr_src, csr_norm);
    gcn_fused_kernel<<<BT, 256, 0, stream>>>(x, W1, b1, W2, b2,
                                             csr_off, csr_src, csr_norm, out);
}

// Round 3
// 223.779 us; speedup vs baseline: 1.6307x; 1.6307x over previous
//
#include <hip/hip_runtime.h>
#include <hip/hip_bf16.h>
#include <math.h>

#define J 75
#define EDGES 300
#define MAXE (EDGES + J)   // 375 with self loops
#define HID 64
#define OUTF 256
#define BT 2048
#define CSTR 68            // Cs row stride (pad 64 -> 68 breaks 16-row bank aliasing)
#define MROWS 80           // 75 rows padded to 5 MFMA tiles

typedef __attribute__((ext_vector_type(8))) short short8;
typedef __attribute__((ext_vector_type(4))) float f32x4;

__device__ __forceinline__ unsigned short f32_to_bf16_rn(float f) {
    unsigned u = __float_as_uint(f);
    unsigned r = u + 0x7FFFu + ((u >> 16) & 1u);
    return (unsigned short)(r >> 16);
}
__device__ __forceinline__ float bf16_to_f32(unsigned short h) {
    return __uint_as_float(((unsigned)h) << 16);
}
__device__ __forceinline__ float gelu_exact(float v) {
    return 0.5f * v * (1.0f + erff(v * 0.70710678118654752f));
}

// ---------------- Kernel 0: build CSR (dst -> [src, norm]) ----------------
__global__ void build_csr_kernel(const int* __restrict__ ei,
                                 int* __restrict__ csr_off,
                                 int* __restrict__ csr_src,
                                 float* __restrict__ csr_norm) {
    __shared__ int   deg[J];
    __shared__ int   off[J + 1];
    __shared__ int   cur[J];
    __shared__ float dis[J];
    const int tid = threadIdx.x;

    if (tid < J) { deg[tid] = 1; cur[tid] = 0; }
    __syncthreads();
    for (int e = tid; e < EDGES; e += blockDim.x)
        atomicAdd(&deg[ei[EDGES + e]], 1);
    __syncthreads();
    if (tid == 0) {
        int s = 0;
        for (int j = 0; j < J; ++j) { off[j] = s; s += deg[j]; }
        off[J] = s;
    }
    if (tid < J) dis[tid] = rsqrtf((float)deg[tid]);
    __syncthreads();
    for (int e = tid; e < EDGES; e += blockDim.x) {
        int s = ei[e], d = ei[EDGES + e];
        int p = off[d] + atomicAdd(&cur[d], 1);
        csr_src[p]  = s;
        csr_norm[p] = dis[s] * dis[d];
    }
    for (int j = tid; j < J; j += blockDim.x) {
        int p = off[j] + atomicAdd(&cur[j], 1);
        csr_src[p]  = j;
        csr_norm[p] = dis[j] * dis[j];
    }
    __syncthreads();
    for (int j = tid; j <= J; j += blockDim.x) csr_off[j] = off[j];
}

// ---------------- Kernel 0b: repack W2 into MFMA B-fragment order, split bf16 hi/lo ----
// Frag (kc,nt): B[k][n], k = kc*32 + (lane>>4)*8 + j, n = nt*16 + (lane&15).
// Linear index t = (((kc*16 + nt)*64) + lane)*8 + j  -> lane-contiguous 16B chunks.
__global__ void repack_w2_kernel(const float* __restrict__ W2,
                                 unsigned short* __restrict__ Whi,
                                 unsigned short* __restrict__ Wlo) {
    int t = blockIdx.x * 256 + threadIdx.x;   // 0 .. 16383
    int j    = t & 7;
    int lane = (t >> 3) & 63;
    int nt   = (t >> 9) & 15;
    int kc   = t >> 13;
    int k = kc * 32 + (lane >> 4) * 8 + j;
    int n = nt * 16 + (lane & 15);
    float w = W2[k * OUTF + n];
    unsigned short hi = f32_to_bf16_rn(w);
    float lo = w - bf16_to_f32(hi);
    Whi[t] = hi;
    Wlo[t] = f32_to_bf16_rn(lo);
}

// ---------------- Kernel 1: fused 2-layer GCN, one block per (b,t) ----------------
__global__ void __launch_bounds__(256, 2) gcn_fused_kernel(
        const float* __restrict__ xg,
        const float* __restrict__ W1,
        const float* __restrict__ b1,
        const float* __restrict__ b2,
        const int*   __restrict__ csr_off,
        const int*   __restrict__ csr_src,
        const float* __restrict__ csr_norm,
        const unsigned short* __restrict__ Whi,
        const unsigned short* __restrict__ Wlo,
        float* __restrict__ outg) {
    __shared__ float xs[J * 3];
    __shared__ float ax[J * 3];
    __shared__ float Bs[J * HID];
    __shared__ __align__(16) float Cs[MROWS * CSTR];
    __shared__ float W1s[3 * HID];
    __shared__ float b1s[HID];
    __shared__ float b2s[OUTF];
    __shared__ int   offs[J + 1];
    __shared__ int   srcs[MAXE];
    __shared__ float nrms[MAXE];

    const int tid  = threadIdx.x;
    const int bt   = blockIdx.x;
    const int wv   = tid >> 6;
    const int lane = tid & 63;
    const int quad = lane >> 4;
    const int l16  = lane & 15;

    // ---- stage graph + small weights + x tile ----
    if (tid < J + 1) offs[tid] = csr_off[tid];
    for (int i = tid; i < MAXE; i += 256) { srcs[i] = csr_src[i]; nrms[i] = csr_norm[i]; }
    if (tid < 3 * HID) W1s[tid] = W1[tid];
    if (tid < HID)     b1s[tid] = b1[tid];
    if (tid < OUTF)    b2s[tid] = b2[tid];
    for (int i = tid; i < J * 3; i += 256)
        xs[i] = xg[bt * (J * 3) + i];
    __syncthreads();

    // ---- aggregate x over graph (75 x 3) ----
    for (int idx = tid; idx < J * 3; idx += 256) {
        int j = idx / 3, d = idx - j * 3;
        float s = 0.f;
        int p0 = offs[j], p1 = offs[j + 1];
        for (int p = p0; p < p1; ++p) s += nrms[p] * xs[srcs[p] * 3 + d];
        ax[idx] = s;
    }
    __syncthreads();

    // ---- layer 1: matmul (3->64) + bias + gelu ----
    for (int idx = tid; idx < J * HID; idx += 256) {
        int j = idx >> 6, f = idx & 63;
        float v = ax[j * 3 + 0] * W1s[0 * HID + f]
                + ax[j * 3 + 1] * W1s[1 * HID + f]
                + ax[j * 3 + 2] * W1s[2 * HID + f]
                + b1s[f];
        Bs[idx] = gelu_exact(v);
    }
    __syncthreads();

    // ---- aggregate layer-1 activations into Cs (75 x 64, stride 68) ----
    for (int idx = tid; idx < J * HID; idx += 256) {
        int j = idx >> 6, f = idx & 63;
        float s = 0.f;
        int p0 = offs[j], p1 = offs[j + 1];
        for (int p = p0; p < p1; ++p) s += nrms[p] * Bs[srcs[p] * HID + f];
        Cs[j * CSTR + f] = s;
    }
    // zero pad rows 75..79 (cols 0..63) so MFMA A-frags are clean
    for (int idx = tid; idx < (MROWS - J) * HID; idx += 256) {
        int j = J + (idx >> 6), f = idx & 63;
        Cs[j * CSTR + f] = 0.f;
    }
    __syncthreads();

    // ---- layer 2 via MFMA: out(75x256) = Cs(75x64) @ W2(64x256), split-bf16 3-MFMA ----
    // Wave wv owns output columns [wv*64, wv*64+64) = 4 n-tiles.
    f32x4 acc[5][4] = {};
    const short8* Whi8 = (const short8*)Whi;
    const short8* Wlo8 = (const short8*)Wlo;

#pragma unroll
    for (int kc = 0; kc < 2; ++kc) {
        short8 bhi[4], blo[4];
#pragma unroll
        for (int n4 = 0; n4 < 4; ++n4) {
            int nt = wv * 4 + n4;
            int fi = (kc * 16 + nt) * 64 + lane;     // coalesced 16B/lane
            bhi[n4] = Whi8[fi];
            blo[n4] = Wlo8[fi];
        }
#pragma unroll
        for (int mt = 0; mt < 5; ++mt) {
            const float* ar = &Cs[(mt * 16 + l16) * CSTR + kc * 32 + quad * 8];
            f32x4 a0 = *(const f32x4*)ar;
            f32x4 a1 = *(const f32x4*)(ar + 4);
            float av[8] = {a0.x, a0.y, a0.z, a0.w, a1.x, a1.y, a1.z, a1.w};
            short8 ahi, alo;
#pragma unroll
            for (int i = 0; i < 8; ++i) {
                unsigned short h = f32_to_bf16_rn(av[i]);
                ahi[i] = (short)h;
                alo[i] = (short)f32_to_bf16_rn(av[i] - bf16_to_f32(h));
            }
#pragma unroll
            for (int n4 = 0; n4 < 4; ++n4) {
                acc[mt][n4] = __builtin_amdgcn_mfma_f32_16x16x32_bf16(ahi, bhi[n4], acc[mt][n4], 0, 0, 0);
                acc[mt][n4] = __builtin_amdgcn_mfma_f32_16x16x32_bf16(ahi, blo[n4], acc[mt][n4], 0, 0, 0);
                acc[mt][n4] = __builtin_amdgcn_mfma_f32_16x16x32_bf16(alo, bhi[n4], acc[mt][n4], 0, 0, 0);
            }
        }
    }

    // ---- epilogue: bias + gelu + store. C/D layout: col=lane&15, row=quad*4+reg ----
    float* outb = outg + (size_t)bt * (J * OUTF);
#pragma unroll
    for (int mt = 0; mt < 5; ++mt) {
#pragma unroll
        for (int n4 = 0; n4 < 4; ++n4) {
            int o = wv * 64 + n4 * 16 + l16;
            float bias = b2s[o];
#pragma unroll
            for (int r = 0; r < 4; ++r) {
                int row = mt * 16 + quad * 4 + r;
                if (row < J)
                    outb[row * OUTF + o] = gelu_exact(acc[mt][n4][r] + bias);
            }
        }
    }
}

extern "C" void kernel_launch(void* const* d_in, const int* in_sizes, int n_in,
                              void* d_out, int out_size, void* d_ws, size_t ws_size,
                              hipStream_t stream) {
    const float* x  = (const float*)d_in[0];
    const int*   ei = (const int*)d_in[1];
    const float* W1 = (const float*)d_in[2];
    const float* b1 = (const float*)d_in[3];
    const float* W2 = (const float*)d_in[4];
    const float* b2 = (const float*)d_in[5];
    float* out = (float*)d_out;

    char* ws = (char*)d_ws;
    int*   csr_off  = (int*)ws;                            // 76 ints
    int*   csr_src  = (int*)(ws + 512);                    // 375 ints
    float* csr_norm = (float*)(ws + 512 + 2048);           // 375 floats
    unsigned short* Whi = (unsigned short*)(ws + 4096);    // 16384 bf16 = 32 KB
    unsigned short* Wlo = (unsigned short*)(ws + 4096 + 32768);

    build_csr_kernel<<<1, 256, 0, stream>>>(ei, csr_off, csr_src, csr_norm);
    repack_w2_kernel<<<64, 256, 0, stream>>>(W2, Whi, Wlo);
    gcn_fused_kernel<<<BT, 256, 0, stream>>>(x, W1, b1, b2,
                                             csr_off, csr_src, csr_norm,
                                             Whi, Wlo, out);
}

// Round 4
// 221.339 us; speedup vs baseline: 1.6487x; 1.0110x over previous
//
#include <hip/hip_runtime.h>
#include <hip/hip_bf16.h>
#include <math.h>

#define J 75
#define EDGES 300
#define MAXE (EDGES + J)   // 375 with self loops
#define HID 64
#define OUTF 256
#define BT 2048
#define MROWS 80           // 75 rows padded to 5 MFMA m-tiles
#define CSP 152            // Cs packed row stride (ushorts): hi[0,64) lo[64,128) pad->152
                           // byte stride 304: 16B-aligned frags, start-bank 4*(3r+q)%32 -> conflict-free

typedef __attribute__((ext_vector_type(8))) short short8;
typedef __attribute__((ext_vector_type(4))) float f32x4;

__device__ __forceinline__ unsigned short f32_to_bf16_rn(float f) {
    unsigned u = __float_as_uint(f);
    unsigned r = u + 0x7FFFu + ((u >> 16) & 1u);
    return (unsigned short)(r >> 16);
}
__device__ __forceinline__ float bf16_to_f32(unsigned short h) {
    return __uint_as_float(((unsigned)h) << 16);
}

// exact-grade gelu: erf via Abramowitz-Stegun 7.1.26, |eps| <= 1.5e-7
__device__ __forceinline__ float gelu_fast(float v) {
    float u = 0.70710678118654752f * v;
    float a = fabsf(u);
    float t = __builtin_amdgcn_rcpf(fmaf(0.3275911f, a, 1.0f));
    float p = t * fmaf(t, fmaf(t, fmaf(t, fmaf(t, 1.061405429f, -1.453152027f),
                                       1.421413741f), -0.284496736f), 0.254829592f);
    float e = __expf(-a * a);
    float erfa = fmaf(-p, e, 1.0f);          // erf(|u|)
    float erfu = copysignf(erfa, u);
    return 0.5f * v * (1.0f + erfu);
}

// ---------------- Kernel 0: prep. Blocks 0..63 repack W2; block 64 builds CSR ----------
__global__ void prep_kernel(const int* __restrict__ ei,
                            const float* __restrict__ W2,
                            int* __restrict__ csr_off,
                            unsigned short* __restrict__ csr_src,
                            float* __restrict__ csr_norm,
                            unsigned short* __restrict__ Whi,
                            unsigned short* __restrict__ Wlo) {
    __shared__ int   deg[J];
    __shared__ int   off[J + 1];
    __shared__ int   cur[J];
    __shared__ float dis[J];
    const int tid = threadIdx.x;

    if (blockIdx.x < 64) {
        // repack W2 into MFMA B-fragment order, split bf16 hi/lo.
        // B[k][n], k = kc*32 + (lane>>4)*8 + j, n = nt*16 + (lane&15)
        int t = blockIdx.x * 256 + tid;      // 0 .. 16383
        int j    = t & 7;
        int lane = (t >> 3) & 63;
        int nt   = (t >> 9) & 15;
        int kc   = t >> 13;
        int k = kc * 32 + (lane >> 4) * 8 + j;
        int n = nt * 16 + (lane & 15);
        float w = W2[k * OUTF + n];
        unsigned short hi = f32_to_bf16_rn(w);
        float lo = w - bf16_to_f32(hi);
        Whi[t] = hi;
        Wlo[t] = f32_to_bf16_rn(lo);
        return;
    }

    // ---- CSR build (one block) ----
    if (tid < J) { deg[tid] = 1; cur[tid] = 0; }
    __syncthreads();
    for (int e = tid; e < EDGES; e += 256)
        atomicAdd(&deg[ei[EDGES + e]], 1);
    __syncthreads();
    if (tid == 0) {
        int s = 0;
        for (int j = 0; j < J; ++j) { off[j] = s; s += deg[j]; }
        off[J] = s;
    }
    if (tid < J) dis[tid] = rsqrtf((float)deg[tid]);
    __syncthreads();
    for (int e = tid; e < EDGES; e += 256) {
        int s = ei[e], d = ei[EDGES + e];
        int p = off[d] + atomicAdd(&cur[d], 1);
        csr_src[p]  = (unsigned short)s;
        csr_norm[p] = dis[s] * dis[d];
    }
    for (int j = tid; j < J; j += 256) {
        int p = off[j] + atomicAdd(&cur[j], 1);
        csr_src[p]  = (unsigned short)j;
        csr_norm[p] = dis[j] * dis[j];
    }
    __syncthreads();
    for (int j = tid; j <= J; j += 256) csr_off[j] = off[j];
}

// ---------------- Kernel 1: fused 2-layer GCN, one block per (b,t) ----------------
__global__ void __launch_bounds__(256, 3) gcn_fused_kernel(
        const float* __restrict__ xg,
        const float* __restrict__ W1,
        const float* __restrict__ b1,
        const float* __restrict__ b2,
        const int*   __restrict__ csr_off,
        const unsigned short* __restrict__ csr_src,
        const float* __restrict__ csr_norm,
        const unsigned short* __restrict__ Whi,
        const unsigned short* __restrict__ Wlo,
        float* __restrict__ outg) {
    __shared__ float xs[J * 3];
    __shared__ float ax[J * 3];
    __shared__ float Bs[J * HID];
    __shared__ __align__(16) unsigned short Csp[MROWS * CSP];  // bf16 hi/lo packed
    __shared__ float W1s[3 * HID];
    __shared__ float b1s[HID];
    __shared__ float b2s[OUTF];
    __shared__ int   offs[J + 1];
    __shared__ unsigned short srcs[MAXE];
    __shared__ float nrms[MAXE];

    const int tid  = threadIdx.x;
    const int bt   = blockIdx.x;
    const int wv   = tid >> 6;
    const int lane = tid & 63;
    const int quad = lane >> 4;
    const int l16  = lane & 15;

    // ---- stage graph + small weights + x tile ----
    if (tid < J + 1) offs[tid] = csr_off[tid];
    for (int i = tid; i < MAXE; i += 256) { srcs[i] = csr_src[i]; nrms[i] = csr_norm[i]; }
    if (tid < 3 * HID) W1s[tid] = W1[tid];
    if (tid < HID)     b1s[tid] = b1[tid];
    if (tid < OUTF)    b2s[tid] = b2[tid];
    for (int i = tid; i < J * 3; i += 256)
        xs[i] = xg[bt * (J * 3) + i];
    __syncthreads();

    // ---- aggregate x over graph (75 x 3) ----
    for (int idx = tid; idx < J * 3; idx += 256) {
        int j = idx / 3, d = idx - j * 3;
        float s = 0.f;
        int p0 = offs[j], p1 = offs[j + 1];
        for (int p = p0; p < p1; ++p) s += nrms[p] * xs[srcs[p] * 3 + d];
        ax[idx] = s;
    }
    __syncthreads();

    // ---- layer 1: matmul (3->64) + bias + gelu ----
    for (int idx = tid; idx < J * HID; idx += 256) {
        int j = idx >> 6, f = idx & 63;
        float v = ax[j * 3 + 0] * W1s[0 * HID + f]
                + ax[j * 3 + 1] * W1s[1 * HID + f]
                + ax[j * 3 + 2] * W1s[2 * HID + f]
                + b1s[f];
        Bs[idx] = gelu_fast(v);
    }
    __syncthreads();

    // ---- aggregate layer-1 activations -> Csp as bf16 hi/lo (2-way unrolled gather) ----
    for (int idx = tid; idx < J * HID; idx += 256) {
        int j = idx >> 6, f = idx & 63;           // j wave-uniform, f = lane
        float s = 0.f, s2 = 0.f;
        int p0 = offs[j], p1 = offs[j + 1];
        int p = p0;
        for (; p + 1 < p1; p += 2) {
            int a = srcs[p], b = srcs[p + 1];
            float na = nrms[p], nb = nrms[p + 1];
            s  += na * Bs[a * HID + f];
            s2 += nb * Bs[b * HID + f];
        }
        if (p < p1) s += nrms[p] * Bs[srcs[p] * HID + f];
        s += s2;
        unsigned short hi = f32_to_bf16_rn(s);
        unsigned short lo = f32_to_bf16_rn(s - bf16_to_f32(hi));
        Csp[j * CSP + f]      = hi;
        Csp[j * CSP + 64 + f] = lo;
    }
    // zero the 5 pad rows (hi+lo)
    for (int idx = tid; idx < (MROWS - J) * 128; idx += 256) {
        int j = J + (idx >> 7), c = idx & 127;
        Csp[j * CSP + c] = 0;
    }
    __syncthreads();

    // ---- layer 2 via MFMA: out(75x256) = Cs(75x64) @ W2(64x256), split-bf16 3-MFMA ----
    // Wave wv owns output columns [wv*64, wv*64+64) = 4 n-tiles. Bias pre-loaded into acc.
    f32x4 acc[5][4];
#pragma unroll
    for (int n4 = 0; n4 < 4; ++n4) {
        float bv = b2s[wv * 64 + n4 * 16 + l16];   // C/D col = lane&15 -> reg-uniform
#pragma unroll
        for (int mt = 0; mt < 5; ++mt)
            acc[mt][n4] = (f32x4){bv, bv, bv, bv};
    }

    const short8* Whi8 = (const short8*)Whi;
    const short8* Wlo8 = (const short8*)Wlo;
#pragma unroll
    for (int kc = 0; kc < 2; ++kc) {
        short8 bhi[4], blo[4];
#pragma unroll
        for (int n4 = 0; n4 < 4; ++n4) {
            int nt = wv * 4 + n4;
            int fi = (kc * 16 + nt) * 64 + lane;   // coalesced 16B/lane, L2-resident
            bhi[n4] = Whi8[fi];
            blo[n4] = Wlo8[fi];
        }
#pragma unroll
        for (int mt = 0; mt < 5; ++mt) {
            const unsigned short* ar = &Csp[(mt * 16 + l16) * CSP + kc * 32 + quad * 8];
            short8 ahi = *(const short8*)ar;          // ds_read_b128
            short8 alo = *(const short8*)(ar + 64);   // ds_read_b128
#pragma unroll
            for (int n4 = 0; n4 < 4; ++n4) {
                acc[mt][n4] = __builtin_amdgcn_mfma_f32_16x16x32_bf16(ahi, bhi[n4], acc[mt][n4], 0, 0, 0);
                acc[mt][n4] = __builtin_amdgcn_mfma_f32_16x16x32_bf16(ahi, blo[n4], acc[mt][n4], 0, 0, 0);
                acc[mt][n4] = __builtin_amdgcn_mfma_f32_16x16x32_bf16(alo, bhi[n4], acc[mt][n4], 0, 0, 0);
            }
        }
    }

    // ---- epilogue: gelu + store. C/D layout: col=lane&15, row=quad*4+reg ----
    float* outb = outg + (size_t)bt * (J * OUTF);
#pragma unroll
    for (int mt = 0; mt < 5; ++mt) {
#pragma unroll
        for (int n4 = 0; n4 < 4; ++n4) {
            int o = wv * 64 + n4 * 16 + l16;
#pragma unroll
            for (int r = 0; r < 4; ++r) {
                int row = mt * 16 + quad * 4 + r;
                if (row < J)
                    outb[row * OUTF + o] = gelu_fast(acc[mt][n4][r]);
            }
        }
    }
}

extern "C" void kernel_launch(void* const* d_in, const int* in_sizes, int n_in,
                              void* d_out, int out_size, void* d_ws, size_t ws_size,
                              hipStream_t stream) {
    const float* x  = (const float*)d_in[0];
    const int*   ei = (const int*)d_in[1];
    const float* W1 = (const float*)d_in[2];
    const float* b1 = (const float*)d_in[3];
    const float* W2 = (const float*)d_in[4];
    const float* b2 = (const float*)d_in[5];
    float* out = (float*)d_out;

    char* ws = (char*)d_ws;
    int*            csr_off  = (int*)ws;                         // 76 ints
    unsigned short* csr_src  = (unsigned short*)(ws + 512);      // 375 ushorts
    float*          csr_norm = (float*)(ws + 2048);              // 375 floats
    unsigned short* Whi      = (unsigned short*)(ws + 4096);     // 16384 bf16 = 32 KB
    unsigned short* Wlo      = (unsigned short*)(ws + 4096 + 32768);

    prep_kernel<<<65, 256, 0, stream>>>(ei, W2, csr_off, csr_src, csr_norm, Whi, Wlo);
    gcn_fused_kernel<<<BT, 256, 0, stream>>>(x, W1, b1, b2,
                                             csr_off, csr_src, csr_norm,
                                             Whi, Wlo, out);
}

// Round 5
// 209.575 us; speedup vs baseline: 1.7413x; 1.0561x over previous
//
#include <hip/hip_runtime.h>
#include <hip/hip_bf16.h>
#include <math.h>

#define J 75
#define EDGES 300
#define MAXE (EDGES + J)
#define HID 64
#define OUTF 256
#define BT 2048
#define BSPW 66           // Bsp row width in uints (64 + 2 pad -> 2-way banks max)
#define BSPROWS 96        // k rows padded to 3 K-chunks of 32
#define CSTR2 72          // Csp plane row stride in ushorts (144B: 16B-aligned, 2-way banks)

typedef __attribute__((ext_vector_type(8))) short short8;
typedef __attribute__((ext_vector_type(4))) float f32x4;

__device__ __forceinline__ unsigned short f32_to_bf16_rn(float f) {
    unsigned u = __float_as_uint(f);
    unsigned r = u + 0x7FFFu + ((u >> 16) & 1u);
    return (unsigned short)(r >> 16);
}
__device__ __forceinline__ float bf16_to_f32(unsigned short h) {
    return __uint_as_float(((unsigned)h) << 16);
}
// tanh-form gelu: max |err| vs exact-erf gelu ~3e-4
__device__ __forceinline__ float gelu_fast(float v) {
    float v2 = v * v;
    float t  = fmaf(v2, 0.044715f, 1.0f);
    float z  = 0.7978845608028654f * v * t;        // gelu = v * sigmoid(2z)
    float e  = __expf(2.0f * z);
    float r  = __builtin_amdgcn_rcpf(e + 1.0f);
    return v * (1.0f - r);
}

// ---------------- Kernel 0: prep ----------------
// blocks 0..63: W2 -> MFMA B-frag order, split bf16 hi/lo
// block 64:     CSR (for x-aggregation)
// block 65:     dense Ahat -> MFMA A-frag order, split bf16 hi/lo
__global__ void prep_kernel(const int* __restrict__ ei,
                            const float* __restrict__ W2,
                            int* __restrict__ csr_off,
                            unsigned short* __restrict__ csr_src,
                            float* __restrict__ csr_norm,
                            unsigned short* __restrict__ Whi,
                            unsigned short* __restrict__ Wlo,
                            unsigned short* __restrict__ Ahi,
                            unsigned short* __restrict__ Alo) {
    const int tid = threadIdx.x;

    if (blockIdx.x < 64) {
        // B[k][n]: k = kc*32 + quad*8 + j, n = nt*16 + l16; linear t = ((kc*16+nt)*64+lane)*8+j
        int t = blockIdx.x * 256 + tid;
        int j    = t & 7;
        int lane = (t >> 3) & 63;
        int nt   = (t >> 9) & 15;
        int kc   = t >> 13;
        int k = kc * 32 + (lane >> 4) * 8 + j;
        int n = nt * 16 + (lane & 15);
        float w = W2[k * OUTF + n];
        unsigned short hi = f32_to_bf16_rn(w);
        Whi[t] = hi;
        Wlo[t] = f32_to_bf16_rn(w - bf16_to_f32(hi));
        return;
    }

    if (blockIdx.x == 64) {
        __shared__ int   deg[J];
        __shared__ int   off[J + 1];
        __shared__ int   cur[J];
        __shared__ float dis[J];
        if (tid < J) { deg[tid] = 1; cur[tid] = 0; }
        __syncthreads();
        for (int e = tid; e < EDGES; e += 256) atomicAdd(&deg[ei[EDGES + e]], 1);
        __syncthreads();
        if (tid == 0) {
            int s = 0;
            for (int j = 0; j < J; ++j) { off[j] = s; s += deg[j]; }
            off[J] = s;
        }
        if (tid < J) dis[tid] = rsqrtf((float)deg[tid]);
        __syncthreads();
        for (int e = tid; e < EDGES; e += 256) {
            int s = ei[e], d = ei[EDGES + e];
            int p = off[d] + atomicAdd(&cur[d], 1);
            csr_src[p]  = (unsigned short)s;
            csr_norm[p] = dis[s] * dis[d];
        }
        for (int j = tid; j < J; j += 256) {
            int p = off[j] + atomicAdd(&cur[j], 1);
            csr_src[p]  = (unsigned short)j;
            csr_norm[p] = dis[j] * dis[j];
        }
        __syncthreads();
        for (int j = tid; j <= J; j += 256) csr_off[j] = off[j];
        return;
    }

    // ---- block 65: dense Ahat[80][96] (zero-padded), then emit A-frags hi/lo ----
    __shared__ float Ad[80 * 96];
    __shared__ int   deg2[J];
    __shared__ float dis2[J];
    for (int i = tid; i < 80 * 96; i += 256) Ad[i] = 0.f;
    if (tid < J) deg2[tid] = 1;
    __syncthreads();
    for (int e = tid; e < EDGES; e += 256) atomicAdd(&deg2[ei[EDGES + e]], 1);
    __syncthreads();
    if (tid < J) dis2[tid] = rsqrtf((float)deg2[tid]);
    __syncthreads();
    for (int e = tid; e < EDGES; e += 256) {
        int s = ei[e], d = ei[EDGES + e];
        atomicAdd(&Ad[d * 96 + s], dis2[s] * dis2[d]);   // multi-edges accumulate
    }
    __syncthreads();
    if (tid < J) Ad[tid * 96 + tid] += dis2[tid] * dis2[tid];  // self loop
    __syncthreads();
    // emit 15 frags (mt 0..4, kc 0..2): A[m][k], m = mt*16+l16, k = kc*32+quad*8+jj
    for (int t = tid; t < 15 * 512; t += 256) {
        int jj   = t & 7;
        int lane = (t >> 3) & 63;
        int f    = t >> 9;               // mt*3 + kc
        int mt = f / 3, kc = f - mt * 3;
        int m = mt * 16 + (lane & 15);
        int k = kc * 32 + (lane >> 4) * 8 + jj;
        float v = Ad[m * 96 + k];
        unsigned short hi = f32_to_bf16_rn(v);
        Ahi[t] = hi;
        Alo[t] = f32_to_bf16_rn(v - bf16_to_f32(hi));
    }
}

// ---------------- Kernel 1: fused 2-layer GCN, one block per (b,t) ----------------
__global__ void __launch_bounds__(256, 4) gcn_fused_kernel(
        const float* __restrict__ xg,
        const float* __restrict__ W1,
        const float* __restrict__ b1,
        const float* __restrict__ b2,
        const int*   __restrict__ csr_off,
        const unsigned short* __restrict__ csr_src,
        const float* __restrict__ csr_norm,
        const unsigned short* __restrict__ Whi,
        const unsigned short* __restrict__ Wlo,
        const unsigned short* __restrict__ Ahi,
        const unsigned short* __restrict__ Alo,
        float* __restrict__ outg) {
    // Union buffer: phase 2-3 = Bsp (hi|lo<<16 packed uints [96][66]);
    // phase 4-5 = Csp hi/lo ushort planes [80][72] each.
    __shared__ __align__(16) unsigned int Ubuf[BSPROWS * BSPW];   // 25344 B
    __shared__ float xs[J * 3];
    __shared__ float ax[J * 3];
    __shared__ float W1s[3 * HID];
    __shared__ float b1s[HID];
    __shared__ float b2s[OUTF];
    __shared__ int   offs[J + 1];
    __shared__ unsigned short srcs[MAXE];
    __shared__ float nrms[MAXE];

    const int tid  = threadIdx.x;
    const int bt   = blockIdx.x;
    const int wv   = tid >> 6;
    const int lane = tid & 63;
    const int quad = lane >> 4;
    const int l16  = lane & 15;

    // ---- stage ----
    if (tid < J + 1) offs[tid] = csr_off[tid];
    for (int i = tid; i < MAXE; i += 256) { srcs[i] = csr_src[i]; nrms[i] = csr_norm[i]; }
    if (tid < 3 * HID) W1s[tid] = W1[tid];
    if (tid < HID)     b1s[tid] = b1[tid];
    if (tid < OUTF)    b2s[tid] = b2[tid];
    for (int i = tid; i < J * 3; i += 256) xs[i] = xg[bt * (J * 3) + i];
    __syncthreads();

    // ---- aggregate x (75 x 3, VALU gather — tiny) ----
    for (int idx = tid; idx < J * 3; idx += 256) {
        int j = idx / 3, d = idx - j * 3;
        float s = 0.f;
        int p0 = offs[j], p1 = offs[j + 1];
        for (int p = p0; p < p1; ++p) s += nrms[p] * xs[srcs[p] * 3 + d];
        ax[idx] = s;
    }
    __syncthreads();

    // ---- layer 1: (3->64) + gelu, write straight into Bsp as bf16 hi/lo ----
    for (int idx = tid; idx < J * HID; idx += 256) {
        int j = idx >> 6, f = idx & 63;
        float v = ax[j * 3 + 0] * W1s[0 * HID + f]
                + ax[j * 3 + 1] * W1s[1 * HID + f]
                + ax[j * 3 + 2] * W1s[2 * HID + f]
                + b1s[f];
        float g = gelu_fast(v);
        unsigned short hi = f32_to_bf16_rn(g);
        unsigned short lo = f32_to_bf16_rn(g - bf16_to_f32(hi));
        Ubuf[j * BSPW + f] = (unsigned)hi | ((unsigned)lo << 16);
    }
    // zero pad rows 75..95 (avoid NaN garbage under 0*x in MFMA)
    for (int idx = tid; idx < (BSPROWS - J) * BSPW; idx += 256) {
        int r = J + idx / BSPW, c = idx - (idx / BSPW) * BSPW;
        Ubuf[r * BSPW + c] = 0u;
    }
    __syncthreads();

    // ---- aggregation via MFMA: C(80x64) = Ahat(80x96) @ B(96x64), split-bf16 3-MFMA ----
    // wave wv owns feature n-tile wv (cols wv*16 .. wv*16+15)
    f32x4 cacc[5] = {};
    const short8* Ahi8 = (const short8*)Ahi;
    const short8* Alo8 = (const short8*)Alo;
#pragma unroll
    for (int kc = 0; kc < 3; ++kc) {
        unsigned w[8];
#pragma unroll
        for (int jj = 0; jj < 8; ++jj)
            w[jj] = Ubuf[(kc * 32 + quad * 8 + jj) * BSPW + wv * 16 + l16];
        short8 bh, bl;
#pragma unroll
        for (int jj = 0; jj < 8; ++jj) {
            bh[jj] = (short)(w[jj] & 0xFFFFu);
            bl[jj] = (short)(w[jj] >> 16);
        }
#pragma unroll
        for (int mt = 0; mt < 5; ++mt) {
            short8 ah = Ahi8[(mt * 3 + kc) * 64 + lane];   // L2-resident, coalesced
            short8 al = Alo8[(mt * 3 + kc) * 64 + lane];
            cacc[mt] = __builtin_amdgcn_mfma_f32_16x16x32_bf16(ah, bh, cacc[mt], 0, 0, 0);
            cacc[mt] = __builtin_amdgcn_mfma_f32_16x16x32_bf16(ah, bl, cacc[mt], 0, 0, 0);
            cacc[mt] = __builtin_amdgcn_mfma_f32_16x16x32_bf16(al, bh, cacc[mt], 0, 0, 0);
        }
    }
    __syncthreads();   // all waves done reading Bsp before union is rewritten

    // ---- pack C into Csp hi/lo planes (A-frag friendly layout) ----
    unsigned short* CH = (unsigned short*)Ubuf;
    unsigned short* CL = CH + 80 * CSTR2;
#pragma unroll
    for (int mt = 0; mt < 5; ++mt) {
#pragma unroll
        for (int r = 0; r < 4; ++r) {
            int node = mt * 16 + quad * 4 + r;       // C/D: row=quad*4+reg, col=l16
            int feat = wv * 16 + l16;
            float v = cacc[mt][r];
            unsigned short hi = f32_to_bf16_rn(v);
            unsigned short lo = f32_to_bf16_rn(v - bf16_to_f32(hi));
            CH[node * CSTR2 + feat] = hi;
            CL[node * CSTR2 + feat] = lo;
        }
    }
    __syncthreads();

    // ---- layer 2: out(75x256) = C(75x64) @ W2(64x256), 2 passes x 2 n-tiles ----
    const short8* Whi8 = (const short8*)Whi;
    const short8* Wlo8 = (const short8*)Wlo;
    float* outb = outg + (size_t)bt * (J * OUTF);

#pragma unroll
    for (int p = 0; p < 2; ++p) {
        f32x4 acc[5][2];
#pragma unroll
        for (int q2 = 0; q2 < 2; ++q2) {
            int nt2 = wv * 4 + p * 2 + q2;
            float bv = b2s[nt2 * 16 + l16];
#pragma unroll
            for (int mt = 0; mt < 5; ++mt) acc[mt][q2] = (f32x4){bv, bv, bv, bv};
        }
#pragma unroll
        for (int kc = 0; kc < 2; ++kc) {
            short8 wh[2], wl[2];
#pragma unroll
            for (int q2 = 0; q2 < 2; ++q2) {
                int nt2 = wv * 4 + p * 2 + q2;
                int fi = (kc * 16 + nt2) * 64 + lane;
                wh[q2] = Whi8[fi];
                wl[q2] = Wlo8[fi];
            }
#pragma unroll
            for (int mt = 0; mt < 5; ++mt) {
                const unsigned short* ab = &CH[(mt * 16 + l16) * CSTR2 + kc * 32 + quad * 8];
                short8 ah = *(const short8*)ab;                       // ds_read_b128
                short8 al = *(const short8*)(ab + 80 * CSTR2);        // lo plane
#pragma unroll
                for (int q2 = 0; q2 < 2; ++q2) {
                    acc[mt][q2] = __builtin_amdgcn_mfma_f32_16x16x32_bf16(ah, wh[q2], acc[mt][q2], 0, 0, 0);
                    acc[mt][q2] = __builtin_amdgcn_mfma_f32_16x16x32_bf16(ah, wl[q2], acc[mt][q2], 0, 0, 0);
                    acc[mt][q2] = __builtin_amdgcn_mfma_f32_16x16x32_bf16(al, wh[q2], acc[mt][q2], 0, 0, 0);
                }
            }
        }
        // epilogue for this pass
#pragma unroll
        for (int mt = 0; mt < 5; ++mt) {
#pragma unroll
            for (int q2 = 0; q2 < 2; ++q2) {
                int o = (wv * 4 + p * 2 + q2) * 16 + l16;
#pragma unroll
                for (int r = 0; r < 4; ++r) {
                    int row = mt * 16 + quad * 4 + r;
                    if (row < J)
                        outb[row * OUTF + o] = gelu_fast(acc[mt][q2][r]);
                }
            }
        }
    }
}

extern "C" void kernel_launch(void* const* d_in, const int* in_sizes, int n_in,
                              void* d_out, int out_size, void* d_ws, size_t ws_size,
                              hipStream_t stream) {
    const float* x  = (const float*)d_in[0];
    const int*   ei = (const int*)d_in[1];
    const float* W1 = (const float*)d_in[2];
    const float* b1 = (const float*)d_in[3];
    const float* W2 = (const float*)d_in[4];
    const float* b2 = (const float*)d_in[5];
    float* out = (float*)d_out;

    char* ws = (char*)d_ws;
    int*            csr_off  = (int*)ws;                          // 304 B
    unsigned short* csr_src  = (unsigned short*)(ws + 512);       // 750 B
    float*          csr_norm = (float*)(ws + 2048);               // 1500 B
    unsigned short* Whi      = (unsigned short*)(ws + 4096);      // 32 KB
    unsigned short* Wlo      = (unsigned short*)(ws + 36864);     // 32 KB
    unsigned short* Ahi      = (unsigned short*)(ws + 69632);     // 15360 B
    unsigned short* Alo      = (unsigned short*)(ws + 86016);     // 15360 B

    prep_kernel<<<66, 256, 0, stream>>>(ei, W2, csr_off, csr_src, csr_norm,
                                        Whi, Wlo, Ahi, Alo);
    gcn_fused_kernel<<<BT, 256, 0, stream>>>(x, W1, b1, b2,
                                             csr_off, csr_src, csr_norm,
                                             Whi, Wlo, Ahi, Alo, out);
}